// Round 3
// baseline (284.751 us; speedup 1.0000x reference)
//
#include <hip/hip_runtime.h>

#define BB  4
#define CC  64
#define HH  128
#define WW  128
#define KS  21
#define PAD 10
#define CH  8            // channels staged per LDS chunk
#define LROW 164         // LDS row stride (floats): 16 zero | 128 data | 20 zero

// Block: 256 threads = 8 h-rows x 32 pixel-quads, one di per block.
// f2 rows staged in LDS (zero-padded). Window consumed quad-by-quad so the
// live register set stays ~100 VGPRs and the compiler keeps acc resident.
__global__ __launch_bounds__(256, 3) void corr_kernel(
    const float* __restrict__ feat1,
    const float* __restrict__ feat2,
    float* __restrict__ out)
{
    __shared__ float lds[CH * 8 * LROW];   // 8ch x 8rows x 164 = 41 KB

    const int tid = threadIdx.x;
    int bi = blockIdx.x;
    const int di = bi % KS;  bi /= KS;
    const int h8 = bi % (HH / 8);
    const int b  = bi / (HH / 8);

    // Zero pad columns: per (ch,row) 9 float4s (4 left, 5 right). 64 rows x 9.
    for (int idx = tid; idx < 64 * 9; idx += 256) {
        const int rr = idx / 9;
        const int qq = idx % 9;
        const int col = (qq < 4) ? (qq << 2) : (144 + ((qq - 4) << 2));
        *(float4*)&lds[rr * LROW + col] = make_float4(0.f, 0.f, 0.f, 0.f);
    }

    const int h  = h8 * 8 + (tid >> 5);
    const int w0 = (tid & 31) << 2;
    const int r0 = h8 * 8 + di - PAD;      // f2 row for local row 0

    // staging assignment: thread -> (row, quad), one float4 per channel
    const int s_q   = tid & 31;
    const int s_row = (tid >> 5) & 7;
    const int sr    = r0 + s_row;
    const bool s_ok = (sr >= 0) && (sr < HH);
    const float* f2p = feat2 + ((size_t)(b * CC) * HH + (s_ok ? sr : 0)) * WW + (s_q << 2);
    float* ldst = &lds[s_row * LROW + 16 + (s_q << 2)];

    const float* f1p = feat1 + ((size_t)(b * CC) * HH + h) * WW + w0;

    float acc[4][KS];
#pragma unroll
    for (int p = 0; p < 4; ++p)
#pragma unroll
        for (int d = 0; d < KS; ++d) acc[p][d] = 0.0f;

    for (int c0 = 0; c0 < CC; c0 += CH) {
        __syncthreads();
#pragma unroll
        for (int cl = 0; cl < CH; ++cl) {
            float4 v = make_float4(0.f, 0.f, 0.f, 0.f);
            if (s_ok)
                v = *(const float4*)(f2p + (size_t)(c0 + cl) * (HH * WW));
            *(float4*)(ldst + cl * (8 * LROW)) = v;
        }
        __syncthreads();

#pragma unroll
        for (int cl = 0; cl < CH; ++cl) {
            const float4 av = *(const float4*)(f1p + (size_t)(c0 + cl) * (HH * WW));
            const float a[4] = {av.x, av.y, av.z, av.w};
            // padded col of window element k (k=0..27) = 16 + w0 - 12 + k
            const float* wp = &lds[(cl * 8 + (tid >> 5)) * LROW + 4 + w0];
            // consume window quad-by-quad: k = p + d + 2  ->  d = k - 2 - p
#pragma unroll
            for (int q = 0; q < 7; ++q) {
                const float4 t = *(const float4*)(wp + (q << 2));
                const float tv[4] = {t.x, t.y, t.z, t.w};
#pragma unroll
                for (int e = 0; e < 4; ++e) {
                    const int k = 4 * q + e;
#pragma unroll
                    for (int p = 0; p < 4; ++p) {
                        const int d = k - 2 - p;
                        if (d >= 0 && d < KS)
                            acc[p][d] += a[p] * tv[e];
                    }
                }
            }
        }
    }

    const float scale = 1.0f / (float)CC;
    float* op = out + (((size_t)b * (KS * KS) + (size_t)di * KS) * HH + h) * WW + w0;
#pragma unroll
    for (int d = 0; d < KS; ++d) {
        float4 v = make_float4(acc[0][d] * scale, acc[1][d] * scale,
                               acc[2][d] * scale, acc[3][d] * scale);
        *(float4*)(op + (size_t)d * (HH * WW)) = v;
    }
}

extern "C" void kernel_launch(void* const* d_in, const int* in_sizes, int n_in,
                              void* d_out, int out_size, void* d_ws, size_t ws_size,
                              hipStream_t stream) {
    const float* feat1 = (const float*)d_in[0];
    const float* feat2 = (const float*)d_in[1];
    float* out = (float*)d_out;

    const int blocks = BB * (HH / 8) * KS;   // 1344
    corr_kernel<<<blocks, 256, 0, stream>>>(feat1, feat2, out);
}